// Round 1
// baseline (2156.227 us; speedup 1.0000x reference)
//
#include <hip/hip_runtime.h>

// GNN_Sine: 4-layer per-joint GCN, fused in one kernel.
// B=65536, NJ=24, dims 13 -> 64 -> 64 -> 64 -> 65.
// Per layer: h[b,k,j] = sum_l n[b,k,l] * w[k,l,j]   (per-node linear)
//            n'[b,n,j] = sum_{m in nbr(n)} aw[n,m] * h[b,m,j] + bias[j]  (tree adjacency)
//            relu between layers (not after last).
// Root joint (0) input is masked to zero.
//
// Design: block = 256 threads (4 waves), TB=8 batch elems/block.
// Two LDS ping-pong buffers [NJ][TB][PF] bf16 (activation storage bf16, all
// arithmetic fp32). Wave owns 6 joints; lane = output feature j (0..63).
// Linear-phase LDS reads are wave-broadcast (same addr for all lanes) -> free.
// Adjacency is static (JOINT_TREES) -> hardcoded neighbor lists (70 edges).

#define NJ 24
#define TB 8
#define PF 68   // padded row stride in bf16 elems: 136 B, 8B-aligned for ushort4

__constant__ int NBR_OFF[NJ + 1] = {0,4,7,10,13,16,19,22,25,28,33,35,37,40,43,46,48,51,54,57,60,63,66,68,70};
__constant__ int NBR_LIST[70] = {
    0,1,2,3,        // n=0  (self + children 1,2,3; parent(0)=0)
    0,1,4,          // n=1
    0,2,5,          // n=2
    0,3,6,          // n=3
    1,4,7,          // n=4
    2,5,8,          // n=5
    3,6,9,          // n=6
    4,7,10,         // n=7
    5,8,11,         // n=8
    6,9,12,13,14,   // n=9
    7,10,           // n=10
    8,11,           // n=11
    9,12,15,        // n=12
    9,13,16,        // n=13
    9,14,17,        // n=14
    12,15,          // n=15
    13,16,18,       // n=16
    14,17,19,       // n=17
    16,18,20,       // n=18
    17,19,21,       // n=19
    18,20,22,       // n=20
    19,21,23,       // n=21
    20,22,          // n=22
    21,23           // n=23
};

__device__ __forceinline__ float bf2f(unsigned short u) {
    return __uint_as_float(((unsigned int)u) << 16);
}
__device__ __forceinline__ unsigned short f2bf(float f) {
    unsigned int u = __float_as_uint(f);
    u += 0x7fffu + ((u >> 16) & 1u);   // round-to-nearest-even
    return (unsigned short)(u >> 16);
}

// One layer: src (activations) -> dst (pre-aggregation h) -> src (next activations)
// DIN: input features. DOUTW: weight row stride (64, or 65 for last layer).
// LAST: 65 output cols (col 64 handled redundantly across lanes), writes fp32 out.
template <int DIN, int DOUTW, bool RELU, bool LAST>
__device__ __forceinline__ void do_layer(
    unsigned short (*src)[TB][PF], unsigned short (*dst)[TB][PF],
    const float* __restrict__ w, const float* __restrict__ aw,
    const float* __restrict__ bias, int lane, int wv,
    float* __restrict__ out, size_t obase)
{
    // ---- phase 1: per-node linear for this wave's 6 joints ----
    for (int kk = 0; kk < 6; ++kk) {
        const int k = wv * 6 + kk;
        const float* wk = w + (size_t)k * DIN * DOUTW;
        float acc[TB];
        float accX[TB];   // col 64 (LAST only), redundant across lanes
#pragma unroll
        for (int b = 0; b < TB; ++b) { acc[b] = 0.f; accX[b] = 0.f; }

        if constexpr (DIN == 13) {
            for (int l = 0; l < 13; ++l) {
                float wl = wk[l * DOUTW + lane];
#pragma unroll
                for (int b = 0; b < TB; ++b)
                    acc[b] += bf2f(src[k][b][l]) * wl;
            }
        } else {
#pragma unroll 4
            for (int l4 = 0; l4 < DIN; l4 += 4) {
                float w0v = wk[(l4 + 0) * DOUTW + lane];
                float w1v = wk[(l4 + 1) * DOUTW + lane];
                float w2v = wk[(l4 + 2) * DOUTW + lane];
                float w3v = wk[(l4 + 3) * DOUTW + lane];
                float wx0 = 0.f, wx1 = 0.f, wx2 = 0.f, wx3 = 0.f;
                if constexpr (LAST) {
                    wx0 = wk[(l4 + 0) * DOUTW + 64];
                    wx1 = wk[(l4 + 1) * DOUTW + 64];
                    wx2 = wk[(l4 + 2) * DOUTW + 64];
                    wx3 = wk[(l4 + 3) * DOUTW + 64];
                }
#pragma unroll
                for (int b = 0; b < TB; ++b) {
                    ushort4 q = *reinterpret_cast<const ushort4*>(&src[k][b][l4]);
                    float n0 = bf2f(q.x), n1 = bf2f(q.y), n2 = bf2f(q.z), n3 = bf2f(q.w);
                    acc[b] += n0 * w0v + n1 * w1v + n2 * w2v + n3 * w3v;
                    if constexpr (LAST)
                        accX[b] += n0 * wx0 + n1 * wx1 + n2 * wx2 + n3 * wx3;
                }
            }
        }
#pragma unroll
        for (int b = 0; b < TB; ++b) {
            dst[k][b][lane] = f2bf(acc[b]);
            if constexpr (LAST) {
                if (lane == 0) dst[k][b][64] = f2bf(accX[b]);
            }
        }
    }
    __syncthreads();   // dst complete before cross-joint reads

    // ---- phase 2: sparse adjacency aggregation + bias (+relu) ----
    for (int kk = 0; kk < 6; ++kk) {
        const int n = wv * 6 + kk;
        float agg[TB];
        float aggX[TB];
#pragma unroll
        for (int b = 0; b < TB; ++b) { agg[b] = 0.f; aggX[b] = 0.f; }
        const int e0 = NBR_OFF[n], e1 = NBR_OFF[n + 1];
        for (int e = e0; e < e1; ++e) {
            const int m = NBR_LIST[e];
            const float c = aw[n * NJ + m];
#pragma unroll
            for (int b = 0; b < TB; ++b)
                agg[b] += c * bf2f(dst[m][b][lane]);
            if constexpr (LAST) {
#pragma unroll
                for (int b = 0; b < TB; ++b)
                    aggX[b] += c * bf2f(dst[m][b][64]);
            }
        }
        const float bb = bias[lane];
        if constexpr (!LAST) {
#pragma unroll
            for (int b = 0; b < TB; ++b) {
                float v = agg[b] + bb;
                if constexpr (RELU) v = fmaxf(v, 0.f);
                src[n][b][lane] = f2bf(v);
            }
        } else {
            const float bX = bias[64];
#pragma unroll
            for (int b = 0; b < TB; ++b) {
                float v = agg[b] + bb;
                size_t o = obase + (size_t)b * (NJ * 65) + n * 65;
                out[o + lane] = v;
                if (lane == 0) out[o + 64] = aggX[b] + bX;
            }
        }
    }
    __syncthreads();   // dst reads done before next layer overwrites it
}

__global__ __launch_bounds__(256) void gnn_fused(
    const float* __restrict__ x,
    const float* __restrict__ w0, const float* __restrict__ aw0, const float* __restrict__ b0,
    const float* __restrict__ w1, const float* __restrict__ aw1, const float* __restrict__ b1,
    const float* __restrict__ w2, const float* __restrict__ aw2, const float* __restrict__ b2,
    const float* __restrict__ w3, const float* __restrict__ aw3, const float* __restrict__ b3,
    float* __restrict__ out)
{
    __shared__ unsigned short A[NJ][TB][PF];   // activations (layer input)
    __shared__ unsigned short H[NJ][TB][PF];   // pre-aggregation h

    const int t = threadIdx.x;
    const int lane = t & 63;
    const int wv = t >> 6;
    const int base = blockIdx.x * TB;

    // Load x tile [TB][24][13] (contiguous TB*312 floats), mask joint 0, cvt bf16.
    for (int i = t; i < TB * NJ * 13; i += 256) {
        const int b = i / (NJ * 13);
        const int r = i % (NJ * 13);
        const int k = r / 13;
        float v = (k == 0) ? 0.f : x[(size_t)(base + b) * 312 + r];
        A[k][b][r % 13] = f2bf(v);
    }
    __syncthreads();

    do_layer<13, 64, true,  false>(A, H, w0, aw0, b0, lane, wv, nullptr, 0);
    do_layer<64, 64, true,  false>(A, H, w1, aw1, b1, lane, wv, nullptr, 0);
    do_layer<64, 64, true,  false>(A, H, w2, aw2, b2, lane, wv, nullptr, 0);
    do_layer<64, 65, false, true >(A, H, w3, aw3, b3, lane, wv, out,
                                   (size_t)base * NJ * 65);
}

extern "C" void kernel_launch(void* const* d_in, const int* in_sizes, int n_in,
                              void* d_out, int out_size, void* d_ws, size_t ws_size,
                              hipStream_t stream)
{
    const float* x   = (const float*)d_in[0];
    const float* w0  = (const float*)d_in[1];
    const float* aw0 = (const float*)d_in[2];
    const float* b0  = (const float*)d_in[3];
    const float* w1  = (const float*)d_in[4];
    const float* aw1 = (const float*)d_in[5];
    const float* b1  = (const float*)d_in[6];
    const float* w2  = (const float*)d_in[7];
    const float* aw2 = (const float*)d_in[8];
    const float* b2  = (const float*)d_in[9];
    const float* w3  = (const float*)d_in[10];
    const float* aw3 = (const float*)d_in[11];
    const float* b3  = (const float*)d_in[12];
    float* out = (float*)d_out;

    const int B = 65536;
    const int blocks = B / TB;   // 8192
    gnn_fused<<<blocks, 256, 0, stream>>>(x, w0, aw0, b0, w1, aw1, b1,
                                          w2, aw2, b2, w3, aw3, b3, out);
}

// Round 2
// 797.586 us; speedup vs baseline: 2.7034x; 2.7034x over previous
//
#include <hip/hip_runtime.h>

// GNN_Sine fused, MFMA edition.
// B=65536, NJ=24, dims 13->64->64->64->65, fp32 in/out.
//
// Per layer: H[b,k,j] = sum_l A[b,k,l]*W[k,l,j]  (per-joint linear, MFMA)
//            A'[b,n,j] = sum_{m in NBR(n)} aw[n,m]*H[b,m,j] + bias[j]  (VALU)
// GEMM orientation (operand swap): C[jout][b] = W^T[jout][l] * Act^T[l][b]
//   A-op = prepacked weight fragments (bf16, global, coalesced dwordx4)
//   B-op = activation fragments (ds_read_b128 from [joint][b][feat] LDS)
//   C rows = 4 consecutive jout at fixed b  -> packed ds_write_b64 back into
//   the SAME [joint][b][feat] layout. One LDS buffer, in-place per phase.
// TB=16 batch/block, 256 threads (4 waves), 55 KB LDS -> 2 blocks/CU.
// Weights prepacked to bf16 MFMA A-fragments in d_ws (737,280 B needed).

#define NJ 24
#define TB 16
#define STR 72          // LDS row stride in bf16 elems (144 B, 16B-aligned)

typedef __attribute__((ext_vector_type(8))) short bf16x8;
typedef __attribute__((ext_vector_type(4))) float f32x4;

__device__ constexpr int NBR_OFF_C[NJ + 1] = {0,4,7,10,13,16,19,22,25,28,33,35,37,40,43,46,48,51,54,57,60,63,66,68,70};
__device__ constexpr int NBR_LIST_C[70] = {
    0,1,2,3,  0,1,4,  0,2,5,  0,3,6,  1,4,7,  2,5,8,  3,6,9,  4,7,10,
    5,8,11,  6,9,12,13,14,  7,10,  8,11,  9,12,15,  9,13,16,  9,14,17,
    12,15,  13,16,18,  14,17,19,  16,18,20,  17,19,21,  18,20,22,  19,21,23,
    20,22,  21,23
};

__device__ __forceinline__ float bf2f(unsigned short u) {
    return __uint_as_float(((unsigned int)u) << 16);
}
__device__ __forceinline__ unsigned short f2bf(float f) {
    unsigned int u = __float_as_uint(f);
    u += 0x7fffu + ((u >> 16) & 1u);   // RNE
    return (unsigned short)(u >> 16);
}
__device__ __forceinline__ unsigned int pack2(float a, float b) {
    return (unsigned int)f2bf(a) | ((unsigned int)f2bf(b) << 16);
}

// ---------------- weight prepack: fp32 [joint][l][jout] -> bf16 A-fragments ----
// Frag layout: elem = frag*512 + lane*8 + j ; lane holds A[m=lane&15][k=(lane>>4)*8+j]
//   m = jout within Mtile, k = l within ktile (K=32).
// Frag index map: L0 (96): (joint*4+mt)         kt=0   base 0
//                 L1 (192): joint*8+mt*2+kt            base 96
//                 L2 (192):                            base 288
//                 L3 (240): joint*10+mt*2+kt (MT=5)    base 480
__global__ __launch_bounds__(256) void prepack(
    const float* __restrict__ w0, const float* __restrict__ w1,
    const float* __restrict__ w2, const float* __restrict__ w3,
    unsigned short* __restrict__ wp)
{
    const int f = blockIdx.x;
    const int t = threadIdx.x;
    const int lane = t >> 2;
    const int jp = t & 3;

    const float* w; int DIN, DOUT, joint, mt, kt;
    if (f < 96)       { w = w0; DIN = 13; DOUT = 64; int g = f;       joint = g >> 2; mt = g & 3;        kt = 0;     }
    else if (f < 288) { w = w1; DIN = 64; DOUT = 64; int g = f - 96;  joint = g >> 3; mt = (g >> 1) & 3; kt = g & 1; }
    else if (f < 480) { w = w2; DIN = 64; DOUT = 64; int g = f - 288; joint = g >> 3; mt = (g >> 1) & 3; kt = g & 1; }
    else              { w = w3; DIN = 64; DOUT = 65; int g = f - 480; joint = g / 10; int r = g % 10; mt = r >> 1; kt = r & 1; }

    const int jout = mt * 16 + (lane & 15);
    unsigned int packed = 0;
#pragma unroll
    for (int jj = 0; jj < 2; ++jj) {
        const int j = jp * 2 + jj;
        const int l = kt * 32 + (lane >> 4) * 8 + j;
        float v = 0.f;
        if (l < DIN && jout < DOUT) v = w[(joint * DIN + l) * DOUT + jout];
        packed |= (unsigned int)f2bf(v) << (16 * jj);
    }
    *(unsigned int*)(wp + (size_t)f * 512 + lane * 8 + jp * 2) = packed;
}

// ---------------- phase 1: per-joint linear via MFMA --------------------------
template<int KT, int MT>
__device__ __forceinline__ void linear_phase(unsigned short* buf,
    const unsigned short* __restrict__ wf, int wv, int lane)
{
    const int bl = lane & 15;       // b (N col)
    const int quad = lane >> 4;
    for (int jj = 0; jj < 6; ++jj) {
        const int k = wv * 6 + jj;
        // B-op: activation fragments (K-contiguous ds_read_b128)
        bf16x8 bfr[KT];
#pragma unroll
        for (int kt = 0; kt < KT; ++kt)
            bfr[kt] = *(bf16x8*)&buf[(k * TB + bl) * STR + kt * 32 + quad * 8];
        // A-op: prepacked weight fragments (coalesced global dwordx4)
        const unsigned short* wj = wf + (size_t)k * (MT * KT * 512) + lane * 8;
        bf16x8 afr[MT][KT];
#pragma unroll
        for (int mt = 0; mt < MT; ++mt)
#pragma unroll
            for (int kt = 0; kt < KT; ++kt)
                afr[mt][kt] = *(const bf16x8*)(wj + (mt * KT + kt) * 512);
        f32x4 acc[MT];
#pragma unroll
        for (int mt = 0; mt < MT; ++mt) {
            acc[mt] = (f32x4){0.f, 0.f, 0.f, 0.f};
#pragma unroll
            for (int kt = 0; kt < KT; ++kt)
                acc[mt] = __builtin_amdgcn_mfma_f32_16x16x32_bf16(afr[mt][kt], bfr[kt], acc[mt], 0, 0, 0);
        }
        // H store: lane holds rows jout = mt*16 + quad*4 .. +3 at col b=bl
        //  -> 4 consecutive feats: packed ds_write_b64, same [joint][b][feat] layout.
#pragma unroll
        for (int mt = 0; mt < MT; ++mt) {
            if (mt < 4 || quad == 0) {    // MT==5: rows 64..79, only quad0 (j 64..67) real
                uint2 p;
                p.x = pack2(acc[mt].x, acc[mt].y);
                p.y = pack2(acc[mt].z, acc[mt].w);
                *(uint2*)&buf[(k * TB + bl) * STR + mt * 16 + quad * 4] = p;
            }
        }
    }
}

// ---------------- phase 2: sparse tree aggregation (VALU) ---------------------
template<bool LAST>
__device__ __forceinline__ void agg_phase(unsigned short* buf,
    const float* __restrict__ aw, const float* __restrict__ bias,
    float* __restrict__ out, int base, int wv, int lane)
{
    const int bsub = lane >> 4;            // 0..3
    const int jq = lane & 15;              // feat quad (4 feats)
    const int b = wv * 4 + bsub;           // 0..15

    float acc[NJ][4];
#pragma unroll
    for (int n = 0; n < NJ; ++n) {
        acc[n][0] = 0.f; acc[n][1] = 0.f; acc[n][2] = 0.f; acc[n][3] = 0.f;
    }
    const float4 bv = *(const float4*)(bias + jq * 4);

    // read each H row once, scatter-add into compile-time-indexed accumulators
#pragma unroll
    for (int m = 0; m < NJ; ++m) {
        uint2 raw = *(uint2*)&buf[(m * TB + b) * STR + jq * 4];
        const float h0 = __uint_as_float(raw.x << 16);
        const float h1 = __uint_as_float(raw.x & 0xffff0000u);
        const float h2 = __uint_as_float(raw.y << 16);
        const float h3 = __uint_as_float(raw.y & 0xffff0000u);
#pragma unroll
        for (int e = NBR_OFF_C[m]; e < NBR_OFF_C[m + 1]; ++e) {
            const int n = NBR_LIST_C[e];
            const float c = aw[n * NJ + m];   // uniform -> s_load
            acc[n][0] += c * h0; acc[n][1] += c * h1;
            acc[n][2] += c * h2; acc[n][3] += c * h3;
        }
    }

    if (!LAST) {
#pragma unroll
        for (int n = 0; n < NJ; ++n) {
            const float v0 = fmaxf(acc[n][0] + bv.x, 0.f);
            const float v1 = fmaxf(acc[n][1] + bv.y, 0.f);
            const float v2 = fmaxf(acc[n][2] + bv.z, 0.f);
            const float v3 = fmaxf(acc[n][3] + bv.w, 0.f);
            uint2 p; p.x = pack2(v0, v1); p.y = pack2(v2, v3);
            *(uint2*)&buf[(n * TB + b) * STR + jq * 4] = p;
        }
    } else {
        float* ob = out + (size_t)(base + b) * (NJ * 65);
#pragma unroll
        for (int n = 0; n < NJ; ++n) {
            float* p = ob + n * 65 + jq * 4;
            p[0] = acc[n][0] + bv.x;
            p[1] = acc[n][1] + bv.y;
            p[2] = acc[n][2] + bv.z;
            p[3] = acc[n][3] + bv.w;
        }
        // feature 64 epilogue: lanes 0..23 own one output joint each
        if (lane < NJ) {
            const int n = lane;
            float a64[4] = {0.f, 0.f, 0.f, 0.f};
            for (int e = NBR_OFF_C[n]; e < NBR_OFF_C[n + 1]; ++e) {
                const int m = NBR_LIST_C[e];
                const float c = aw[n * NJ + m];
#pragma unroll
                for (int bb = 0; bb < 4; ++bb)
                    a64[bb] += c * bf2f(buf[(m * TB + wv * 4 + bb) * STR + 64]);
            }
            const float b64v = bias[64];
#pragma unroll
            for (int bb = 0; bb < 4; ++bb)
                out[(size_t)(base + wv * 4 + bb) * (NJ * 65) + n * 65 + 64] = a64[bb] + b64v;
        }
    }
}

// ---------------- main fused kernel -------------------------------------------
__global__ __launch_bounds__(256, 2) void gnn_mfma(
    const float* __restrict__ x, const unsigned short* __restrict__ wp,
    const float* __restrict__ aw0, const float* __restrict__ b0,
    const float* __restrict__ aw1, const float* __restrict__ b1,
    const float* __restrict__ aw2, const float* __restrict__ b2,
    const float* __restrict__ aw3, const float* __restrict__ b3,
    float* __restrict__ out)
{
    __shared__ __align__(16) unsigned short buf[NJ * TB * STR];  // 55,296 B

    const int t = threadIdx.x;
    const int lane = t & 63;
    const int wv = t >> 6;
    const int base = blockIdx.x * TB;

    // load x tile -> [joint][b][feat] bf16, feats 13..31 zeroed (K=32 pad),
    // joint 0 masked to zero (mask_root).
    for (int i = t; i < NJ * TB * 16; i += 256) {
        const int k = i >> 8;            // /(16 pairs * 16 b)
        const int b = (i >> 4) & 15;
        const int f2 = (i & 15) * 2;
        float v0 = 0.f, v1 = 0.f;
        if (k > 0) {
            const float* xr = x + (size_t)(base + b) * 312 + k * 13;
            if (f2 < 13)     v0 = xr[f2];
            if (f2 + 1 < 13) v1 = xr[f2 + 1];
        }
        *(unsigned int*)&buf[(k * TB + b) * STR + f2] = pack2(v0, v1);
    }
    __syncthreads();

    linear_phase<1, 4>(buf, wp, wv, lane);                 // L0: K=32(13+pad)
    __syncthreads();
    agg_phase<false>(buf, aw0, b0, nullptr, base, wv, lane);
    __syncthreads();
    linear_phase<2, 4>(buf, wp + 96 * 512, wv, lane);      // L1
    __syncthreads();
    agg_phase<false>(buf, aw1, b1, nullptr, base, wv, lane);
    __syncthreads();
    linear_phase<2, 4>(buf, wp + 288 * 512, wv, lane);     // L2
    __syncthreads();
    agg_phase<false>(buf, aw2, b2, nullptr, base, wv, lane);
    __syncthreads();
    linear_phase<2, 5>(buf, wp + 480 * 512, wv, lane);     // L3: MT=5 (65 cols)
    __syncthreads();
    agg_phase<true>(buf, aw3, b3, out, base, wv, lane);
}

extern "C" void kernel_launch(void* const* d_in, const int* in_sizes, int n_in,
                              void* d_out, int out_size, void* d_ws, size_t ws_size,
                              hipStream_t stream)
{
    const float* x   = (const float*)d_in[0];
    const float* w0  = (const float*)d_in[1];
    const float* aw0 = (const float*)d_in[2];
    const float* b0  = (const float*)d_in[3];
    const float* w1  = (const float*)d_in[4];
    const float* aw1 = (const float*)d_in[5];
    const float* b1  = (const float*)d_in[6];
    const float* w2  = (const float*)d_in[7];
    const float* aw2 = (const float*)d_in[8];
    const float* b2  = (const float*)d_in[9];
    const float* w3  = (const float*)d_in[10];
    const float* aw3 = (const float*)d_in[11];
    const float* b3  = (const float*)d_in[12];
    float* out = (float*)d_out;
    unsigned short* wp = (unsigned short*)d_ws;   // needs 737,280 B (720 frags * 1 KB)

    prepack<<<720, 256, 0, stream>>>(w0, w1, w2, w3, wp);

    const int blocks = 65536 / TB;   // 4096
    gnn_mfma<<<blocks, 256, 0, stream>>>(x, wp, aw0, b0, aw1, b1,
                                         aw2, b2, aw3, b3, out);
}